// Round 1
// baseline (282.847 us; speedup 1.0000x reference)
//
#include <hip/hip_runtime.h>

// Problem constants: B=2048, V=256, T=11, K=8, N=8, H=255
constexpr int B_ = 2048;
constexpr int V_ = 256;
constexpr int T_ = 11;
constexpr int K_ = 8;
constexpr int N_ = 8;
constexpr int H_ = 255;
constexpr int TK = T_ * K_;          // 88 (t*8+k flat index within a b)
constexpr int XB = V_ * TK;          // 22528 floats per batch element
constexpr int SLAB = 92;             // hsh per-k stride: 28k%32 distinct -> b128 reads conflict-free

// ---------------- kernel 1: streaming one-hot scan -> ids (global) ----------
// R5 split: the fused kernel ran the 184.5 MB streaming read at ~680 GB/s
// (10.8% of peak) because the streaming waves inherited phase-C's ~170-VGPR
// register shape (12 waves/CU, barrier-separated). This kernel is the same
// known-good batched-uint4 scan but with nothing else in the kernel:
// low VGPR -> high occupancy -> loads continuously in flight, like the
// 87%-of-peak fill kernels. Exactly one nonzero per (t,k) entry -> each ids
// slot written exactly once per launch (re-poison safe, no init needed).
__global__ __launch_bounds__(256, 4)
void scan_ids(const float* __restrict__ x,   // (B,V,T,K)
              int* __restrict__ ids)         // (B,88) in workspace
{
    const int tid = threadIdx.x;
    const int b   = blockIdx.x;
    const uint4* xb = (const uint4*)(x + (size_t)b * XB);
    int* __restrict__ idb = ids + b * TK;

    #pragma unroll
    for (int c = 0; c < 3; ++c) {
        const int nload = (c < 2) ? 8 : 6;   // 22 uint4/thread total
        uint4 vbuf[8];
        #pragma unroll
        for (int i = 0; i < 8; ++i)
            if (i < nload) vbuf[i] = xb[(c * 8 + i) * 256 + tid];
        #pragma unroll
        for (int i = 0; i < 8; ++i) {
            if (i < nload) {
                const uint4 q = vbuf[i];
                if (q.x | q.y | q.z | q.w) {   // one-hot: bits are 0 or 0x3F800000
                    const int F = ((c * 8 + i) * 256 + tid) * 4;
                    if (q.x) { const int f = F;     const int v = f / TK; idb[f - v * TK] = v; }
                    if (q.y) { const int f = F + 1; const int v = f / TK; idb[f - v * TK] = v; }
                    if (q.z) { const int f = F + 2; const int v = f / TK; idb[f - v * TK] = v; }
                    if (q.w) { const int f = F + 3; const int v = f / TK; idb[f - v * TK] = v; }
                }
            }
        }
    }
}

// ---------------- kernel 2: gather -> MLP (phases B+C, verbatim R3 shape) ---
// Reads 352 B of ids per block instead of the 88 KB slab; weights (64+65+16 KB)
// are L2-resident broadcast. Compute-bound, ~1 us/block.
__global__ __launch_bounds__(256, 3)
void scanner_mlp(const int* __restrict__ ids,   // (B,88)
                 const float* __restrict__ sw,  // (N,V,K)
                 const float* __restrict__ hw,  // (K*H, N)
                 const float* __restrict__ ow,  // (2, K*H)
                 const float* __restrict__ ob,  // (2,)
                 float* __restrict__ out)       // (B,2,T)
{
    __shared__ int   ids_sh[TK];       // 88
    __shared__ float hsh[K_ * SLAB];   // 736 floats: [k][t*8+n], ReLU'd
    __shared__ float wred[4][22];

    const int tid = threadIdx.x;
    const int b   = blockIdx.x;

    // ---- stage ids ----
    if (tid < TK) ids_sh[tid] = ids[b * TK + tid];
    __syncthreads();

    // ---- phase B: gather sw (L1/L2-resident 64 KB) into hsh, inline ReLU ----
    // 88 entries x 8 n = 704 scalar loads spread over 256 threads (<=3 each).
    // Valid because one-hot coefficient is exactly 1.0: h = relu(sw[n,id,k]).
    #pragma unroll
    for (int j = 0; j < 3; ++j) {
        const int idx = j * 256 + tid;
        if (idx < TK * N_) {
            const int entry = idx >> 3;       // 0..87
            const int n     = idx & 7;
            const int t     = entry >> 3;
            const int k     = entry & 7;
            const int v     = ids_sh[entry];
            hsh[k * SLAB + t * 8 + n] = fmaxf(sw[(n * V_ + v) * K_ + k], 0.0f);
        }
    }
    __syncthreads();

    // ---- phase C: hidden layer + output accumulation (R3 shape) ----
    const int k2 = tid >> 5;   // slot 0..7
    const int hb = tid & 31;

    float hreg[T_][N_];        // broadcast b128 LDS reads (same addr per k2 group)
    #pragma unroll
    for (int t = 0; t < T_; ++t) {
        const float4* p = (const float4*)(hsh + k2 * SLAB + t * 8);
        const float4 a0 = p[0];
        const float4 a1 = p[1];
        hreg[t][0] = a0.x; hreg[t][1] = a0.y; hreg[t][2] = a0.z; hreg[t][3] = a0.w;
        hreg[t][4] = a1.x; hreg[t][5] = a1.y; hreg[t][6] = a1.z; hreg[t][7] = a1.w;
    }

    float acc0[T_], acc1[T_];
    #pragma unroll
    for (int t = 0; t < T_; ++t) { acc0[t] = 0.0f; acc1[t] = 0.0f; }

    #pragma unroll
    for (int i = 0; i < 8; ++i) {
        const int hh = hb + 32 * i;          // 0..255, skip 255
        if (hh < H_) {
            const int row = k2 * H_ + hh;    // coalesced across hb
            const float4* hwp = (const float4*)(hw + row * 8);
            const float4 w0 = hwp[0];
            const float4 w1 = hwp[1];
            const float o0 = ow[row];
            const float o1 = ow[K_ * H_ + row];
            #pragma unroll
            for (int t = 0; t < T_; ++t) {
                float pre = w0.x * hreg[t][0];
                pre = fmaf(w0.y, hreg[t][1], pre);
                pre = fmaf(w0.z, hreg[t][2], pre);
                pre = fmaf(w0.w, hreg[t][3], pre);
                pre = fmaf(w1.x, hreg[t][4], pre);
                pre = fmaf(w1.y, hreg[t][5], pre);
                pre = fmaf(w1.z, hreg[t][6], pre);
                pre = fmaf(w1.w, hreg[t][7], pre);
                const float h2 = fmaxf(pre, 0.0f);
                acc0[t] = fmaf(h2, o0, acc0[t]);
                acc1[t] = fmaf(h2, o1, acc1[t]);
            }
        }
    }

    // ---- reduce: 64-lane butterfly, then cross-wave ----
    #pragma unroll
    for (int t = 0; t < T_; ++t) {
        #pragma unroll
        for (int off = 32; off >= 1; off >>= 1) {
            acc0[t] += __shfl_xor(acc0[t], off, 64);
            acc1[t] += __shfl_xor(acc1[t], off, 64);
        }
    }
    const int wave = tid >> 6;
    const int lane = tid & 63;
    if (lane == 0) {
        #pragma unroll
        for (int t = 0; t < T_; ++t) {
            wred[wave][t]      = acc0[t];
            wred[wave][11 + t] = acc1[t];
        }
    }
    __syncthreads();

    if (tid < 22) {
        const float s = wred[0][tid] + wred[1][tid] + wred[2][tid] + wred[3][tid];
        out[(size_t)b * 22 + tid] = s + ob[tid / 11];
    }
}

extern "C" void kernel_launch(void* const* d_in, const int* in_sizes, int n_in,
                              void* d_out, int out_size, void* d_ws, size_t ws_size,
                              hipStream_t stream) {
    const float* x  = (const float*)d_in[0];  // (B,V,T,K)
    const float* sw = (const float*)d_in[1];  // (N,V,K)
    const float* hw = (const float*)d_in[2];  // (K*H,N)
    const float* ow = (const float*)d_in[3];  // (2,K*H)
    const float* ob = (const float*)d_in[4];  // (2,)
    float* out = (float*)d_out;               // (B,2,T)

    int* ids = (int*)d_ws;                    // 2048*88*4 = 720,896 B << ws_size

    scan_ids<<<B_, 256, 0, stream>>>(x, ids);
    scanner_mlp<<<B_, 256, 0, stream>>>(ids, sw, hw, ow, ob, out);
}

// Round 2
// 278.279 us; speedup vs baseline: 1.0164x; 1.0164x over previous
//
#include <hip/hip_runtime.h>

// Problem constants: B=2048, V=256, T=11, K=8, N=8, H=255
constexpr int B_ = 2048;
constexpr int V_ = 256;
constexpr int T_ = 11;
constexpr int K_ = 8;
constexpr int N_ = 8;
constexpr int H_ = 255;
constexpr int KH_ = K_ * H_;         // 2040
constexpr int TK = T_ * K_;          // 88 (t*8+k flat index within a b)
constexpr int XB = V_ * TK;          // 22528 floats per batch element

// R6 insight: input is exactly one-hot and the whole MLP is per-(k, id):
//   out[b,o,t] = ob[o] + sum_k G[k, id(b,t,k)][o]
//   G[k,v][o]  = sum_h relu( sum_n hw[k,h,n] * relu(sw[n,v,k]) ) * ow[o, k*H+h]
// G is a 8*256*2-float (16 KB) table -> the 0.93-GFLOP MLP, the 704-load
// gather, and the butterfly reduce all collapse into 88 L1-resident float2
// lookups per block. The main kernel is then a pure 184.5 MB stream.

// ---------------- kernel 1: build LUT G2[k*256+v] = (g_o0, g_o1) ------------
// 8192 threads: 4 threads per (k,v) pair, each covering 64 of the 255 hidden
// neurons, quad-reduced via shfl_xor (deterministic). Every G2 slot is
// rewritten each launch (workspace re-poison safe).
__global__ __launch_bounds__(256)
void build_lut(const float* __restrict__ sw,   // (N,V,K)
               const float* __restrict__ hw,   // (K*H, N)
               const float* __restrict__ ow,   // (2, K*H)
               float2* __restrict__ G2)        // (K*V) in workspace
{
    const int g    = blockIdx.x * 256 + threadIdx.x;   // 0..8191
    const int pair = g >> 2;                           // (k,v) 0..2047
    const int q    = g & 3;                            // h-quarter
    const int k    = pair >> 8;
    const int v    = pair & 255;

    float sv[N_];
    #pragma unroll
    for (int n = 0; n < N_; ++n)
        sv[n] = fmaxf(sw[(n * V_ + v) * K_ + k], 0.0f);

    float a0 = 0.0f, a1 = 0.0f;
    const int hbase = q * 64;
    #pragma unroll 8
    for (int j = 0; j < 64; ++j) {
        const int h = hbase + j;
        if (h < H_) {                       // skip h==255 in the last quarter
            const int row = k * H_ + h;
            const float4* hp = (const float4*)(hw + row * 8);
            const float4 w0 = hp[0];
            const float4 w1 = hp[1];
            float pre = w0.x * sv[0];
            pre = fmaf(w0.y, sv[1], pre);
            pre = fmaf(w0.z, sv[2], pre);
            pre = fmaf(w0.w, sv[3], pre);
            pre = fmaf(w1.x, sv[4], pre);
            pre = fmaf(w1.y, sv[5], pre);
            pre = fmaf(w1.z, sv[6], pre);
            pre = fmaf(w1.w, sv[7], pre);
            const float h2 = fmaxf(pre, 0.0f);
            a0 = fmaf(h2, ow[row], a0);
            a1 = fmaf(h2, ow[KH_ + row], a1);
        }
    }
    // quad lanes (q=0..3) are consecutive: reduce within the quad
    a0 += __shfl_xor(a0, 1, 64);
    a0 += __shfl_xor(a0, 2, 64);
    a1 += __shfl_xor(a1, 1, 64);
    a1 += __shfl_xor(a1, 2, 64);
    if (q == 0) G2[pair] = make_float2(a0, a1);
}

// ---------------- kernel 2: stream x -> ids -> LUT sum ----------------------
// Phase A: proven batched-uint4 coalesced scan of the 88 KB slab (exactly one
// nonzero per (t,k); bits of 1.0f are 0x3F800000, zeros are +0 -> integer
// compare). Epilogue: 88 float2 lookups from the 16 KB L1-resident table,
// 8-way add per output. No hidden-layer compute, no global ids round-trip.
__global__ __launch_bounds__(256, 4)
void scan_lookup(const float* __restrict__ x,    // (B,V,T,K)
                 const float2* __restrict__ G2,  // (K*V)
                 const float* __restrict__ ob,   // (2,)
                 float* __restrict__ out)        // (B,2,T)
{
    __shared__ int   ids_sh[TK];   // [t*8+k] -> v
    __shared__ float g0[TK];       // [t*8+k] -> G[k,v][0]
    __shared__ float g1[TK];

    const int tid = threadIdx.x;
    const int b   = blockIdx.x;
    const uint4* xb = (const uint4*)(x + (size_t)b * XB);

    // ---- phase A: scan slab for one-hot indices ----
    #pragma unroll
    for (int c = 0; c < 3; ++c) {
        const int nload = (c < 2) ? 8 : 6;   // 22 uint4/thread total
        uint4 vbuf[8];
        #pragma unroll
        for (int i = 0; i < 8; ++i)
            if (i < nload) vbuf[i] = xb[(c * 8 + i) * 256 + tid];
        #pragma unroll
        for (int i = 0; i < 8; ++i) {
            if (i < nload) {
                const uint4 q = vbuf[i];
                if (q.x | q.y | q.z | q.w) {
                    const int F = ((c * 8 + i) * 256 + tid) * 4;
                    if (q.x) { const int f = F;     const int v = f / TK; ids_sh[f - v * TK] = v; }
                    if (q.y) { const int f = F + 1; const int v = f / TK; ids_sh[f - v * TK] = v; }
                    if (q.z) { const int f = F + 2; const int v = f / TK; ids_sh[f - v * TK] = v; }
                    if (q.w) { const int f = F + 3; const int v = f / TK; ids_sh[f - v * TK] = v; }
                }
            }
        }
    }
    __syncthreads();

    // ---- epilogue: table lookups + per-(o,t) 8-way sum ----
    if (tid < TK) {
        const int k = tid & 7;
        const float2 gg = G2[k * V_ + ids_sh[tid]];
        g0[tid] = gg.x;
        g1[tid] = gg.y;
    }
    __syncthreads();

    if (tid < 22) {
        const int o = tid / 11;            // out[b*22 + tid], tid = o*11 + t
        const int t = tid - o * 11;
        const float* gp = (o ? g1 : g0) + t * 8;
        const float s = ((gp[0] + gp[1]) + (gp[2] + gp[3]))
                      + ((gp[4] + gp[5]) + (gp[6] + gp[7]));
        out[(size_t)b * 22 + tid] = s + ob[o];
    }
}

extern "C" void kernel_launch(void* const* d_in, const int* in_sizes, int n_in,
                              void* d_out, int out_size, void* d_ws, size_t ws_size,
                              hipStream_t stream) {
    const float* x  = (const float*)d_in[0];  // (B,V,T,K)
    const float* sw = (const float*)d_in[1];  // (N,V,K)
    const float* hw = (const float*)d_in[2];  // (K*H,N)
    const float* ow = (const float*)d_in[3];  // (2,K*H)
    const float* ob = (const float*)d_in[4];  // (2,)
    float* out = (float*)d_out;               // (B,2,T)

    float2* G2 = (float2*)d_ws;               // 2048 * 8 B = 16 KB << ws_size

    build_lut<<<32, 256, 0, stream>>>(sw, hw, ow, G2);
    scan_lookup<<<B_, 256, 0, stream>>>(x, G2, ob, out);
}

// Round 4
// 260.021 us; speedup vs baseline: 1.0878x; 1.0702x over previous
//
#include <hip/hip_runtime.h>

// Problem constants: B=2048, V=256, T=11, K=8, N=8, H=255
constexpr int B_ = 2048;
constexpr int V_ = 256;
constexpr int T_ = 11;
constexpr int K_ = 8;
constexpr int N_ = 8;
constexpr int H_ = 255;
constexpr int TK = T_ * K_;          // 88 (t*8+k flat index within a b)
constexpr int XB = V_ * TK;          // 22528 floats per batch element
constexpr int SLAB = 92;             // hsh per-k stride: 28k%32 distinct -> b128 reads conflict-free

// Native clang vector type: __builtin_nontemporal_load requires a vector of
// scalars, not HIP_vector_type (R3 compile failure).
typedef unsigned int uint4v __attribute__((ext_vector_type(4)));

// R8 = R7 with the nt-load type fixed. Single-launch fused structure
// (R0=271.7 with 1 launch beat both 2-launch splits at 278/283; dur_us tracks
// launch count, not kernel content). Deltas vs R0:
//   (a) __builtin_nontemporal_load on the x stream: 184.5 MB use-once traffic
//       no longer evicts the 130 KB weight tables (sw/hw/ow) from L2 that all
//       2048 blocks re-read in phases B/C.
//   (b) integer one-hot detect (bits of 1.0f = 0x3F800000): shorter dep chain.
__global__ __launch_bounds__(256, 3)
void scanner_fused(const float* __restrict__ x,    // (B,V,T,K)
                   const float* __restrict__ sw,   // (N,V,K)
                   const float* __restrict__ hw,   // (K*H, N)
                   const float* __restrict__ ow,   // (2, K*H)
                   const float* __restrict__ ob,   // (2,)
                   float* __restrict__ out)        // (B,2,T)
{
    __shared__ int   ids_sh[TK];       // 88
    __shared__ float hsh[K_ * SLAB];   // 736 floats: [k][t*8+n], ReLU'd
    __shared__ float wred[4][22];

    const int tid = threadIdx.x;
    const int b   = blockIdx.x;

    // ---- phase A: scan slab for one-hot indices (nt loads, int detect) ----
    const uint4v* xb = (const uint4v*)(x + (size_t)b * XB);
    #pragma unroll
    for (int c = 0; c < 3; ++c) {
        const int nload = (c < 2) ? 8 : 6;   // 22 uint4/thread total
        uint4v vbuf[8];
        #pragma unroll
        for (int i = 0; i < 8; ++i)
            if (i < nload) vbuf[i] = __builtin_nontemporal_load(&xb[(c * 8 + i) * 256 + tid]);
        #pragma unroll
        for (int i = 0; i < 8; ++i) {
            if (i < nload) {
                const uint4v q = vbuf[i];
                if (q.x | q.y | q.z | q.w) {   // one-hot: 0x3F800000 or 0
                    const int F = ((c * 8 + i) * 256 + tid) * 4;
                    if (q.x) { const int f = F;     const int v = f / TK; ids_sh[f - v * TK] = v; }
                    if (q.y) { const int f = F + 1; const int v = f / TK; ids_sh[f - v * TK] = v; }
                    if (q.z) { const int f = F + 2; const int v = f / TK; ids_sh[f - v * TK] = v; }
                    if (q.w) { const int f = F + 3; const int v = f / TK; ids_sh[f - v * TK] = v; }
                }
            }
        }
    }
    __syncthreads();

    // ---- phase B: gather sw (L1/L2-resident 64 KB) into hsh, inline ReLU ----
    // 88 entries x 8 n = 704 scalar loads spread over 256 threads (<=3 each).
    // Valid because one-hot coefficient is exactly 1.0: h = relu(sw[n,id,k]).
    #pragma unroll
    for (int j = 0; j < 3; ++j) {
        const int idx = j * 256 + tid;
        if (idx < TK * N_) {
            const int entry = idx >> 3;       // 0..87
            const int n     = idx & 7;
            const int t     = entry >> 3;
            const int k     = entry & 7;
            const int v     = ids_sh[entry];
            hsh[k * SLAB + t * 8 + n] = fmaxf(sw[(n * V_ + v) * K_ + k], 0.0f);
        }
    }
    __syncthreads();

    // ---- phase C: hidden layer + output accumulation (R3 shape) ----
    const int k2 = tid >> 5;   // slot 0..7
    const int hb = tid & 31;

    float hreg[T_][N_];        // broadcast b128 LDS reads (same addr per k2 group)
    #pragma unroll
    for (int t = 0; t < T_; ++t) {
        const float4* p = (const float4*)(hsh + k2 * SLAB + t * 8);
        const float4 a0 = p[0];
        const float4 a1 = p[1];
        hreg[t][0] = a0.x; hreg[t][1] = a0.y; hreg[t][2] = a0.z; hreg[t][3] = a0.w;
        hreg[t][4] = a1.x; hreg[t][5] = a1.y; hreg[t][6] = a1.z; hreg[t][7] = a1.w;
    }

    float acc0[T_], acc1[T_];
    #pragma unroll
    for (int t = 0; t < T_; ++t) { acc0[t] = 0.0f; acc1[t] = 0.0f; }

    #pragma unroll
    for (int i = 0; i < 8; ++i) {
        const int hh = hb + 32 * i;          // 0..255, skip 255
        if (hh < H_) {
            const int row = k2 * H_ + hh;    // coalesced across hb
            const float4* hwp = (const float4*)(hw + row * 8);
            const float4 w0 = hwp[0];
            const float4 w1 = hwp[1];
            const float o0 = ow[row];
            const float o1 = ow[K_ * H_ + row];
            #pragma unroll
            for (int t = 0; t < T_; ++t) {
                float pre = w0.x * hreg[t][0];
                pre = fmaf(w0.y, hreg[t][1], pre);
                pre = fmaf(w0.z, hreg[t][2], pre);
                pre = fmaf(w0.w, hreg[t][3], pre);
                pre = fmaf(w1.x, hreg[t][4], pre);
                pre = fmaf(w1.y, hreg[t][5], pre);
                pre = fmaf(w1.z, hreg[t][6], pre);
                pre = fmaf(w1.w, hreg[t][7], pre);
                const float h2 = fmaxf(pre, 0.0f);
                acc0[t] = fmaf(h2, o0, acc0[t]);
                acc1[t] = fmaf(h2, o1, acc1[t]);
            }
        }
    }

    // ---- reduce: 64-lane butterfly, then cross-wave ----
    #pragma unroll
    for (int t = 0; t < T_; ++t) {
        #pragma unroll
        for (int off = 32; off >= 1; off >>= 1) {
            acc0[t] += __shfl_xor(acc0[t], off, 64);
            acc1[t] += __shfl_xor(acc1[t], off, 64);
        }
    }
    const int wave = tid >> 6;
    const int lane = tid & 63;
    if (lane == 0) {
        #pragma unroll
        for (int t = 0; t < T_; ++t) {
            wred[wave][t]      = acc0[t];
            wred[wave][11 + t] = acc1[t];
        }
    }
    __syncthreads();

    if (tid < 22) {
        const float s = wred[0][tid] + wred[1][tid] + wred[2][tid] + wred[3][tid];
        out[(size_t)b * 22 + tid] = s + ob[tid / 11];
    }
}

extern "C" void kernel_launch(void* const* d_in, const int* in_sizes, int n_in,
                              void* d_out, int out_size, void* d_ws, size_t ws_size,
                              hipStream_t stream) {
    const float* x  = (const float*)d_in[0];  // (B,V,T,K)
    const float* sw = (const float*)d_in[1];  // (N,V,K)
    const float* hw = (const float*)d_in[2];  // (K*H,N)
    const float* ow = (const float*)d_in[3];  // (2,K*H)
    const float* ob = (const float*)d_in[4];  // (2,)
    float* out = (float*)d_out;               // (B,2,T)

    scanner_fused<<<B_, 256, 0, stream>>>(x, sw, hw, ow, ob, out);
}